// Round 1
// baseline (1670.366 us; speedup 1.0000x reference)
//
#include <hip/hip_runtime.h>
#include <math.h>

// Problem constants
constexpr int Bb = 8192;
constexpr int Dd = 40;
constexpr int Tt = 100;
constexpr int Pp = 120;
constexpr int Qq = 100;
constexpr int DT = Dd * Tt;   // 4000
constexpr int PT = Pp * Tt;   // 12000
constexpr int PQ = Pp * Qq;   // 12000

constexpr int NB1 = 8;        // batches per block in phase 1

// LDS strides (floats). All row strides are multiples of 4 floats -> 16B aligned rows.
constexpr int XS_S = 44;      // Xs_t[t][d]   : 100 x 44  = 17.6 KB
constexpr int XW_S = 104;     // XWs[d][s]    : 40 x 104  = 16.64 KB
constexpr int W1_S = 120;     // W1t[d][p]    : 40 x 120  = 19.2 KB
constexpr int TCH  = 20;      // t-chunk size for tem
constexpr int TM_S = 124;     // temt[tl][p]  : 20 x 124  = 9.92 KB

// ---------------------------------------------------------------------------
// Phase 1: S[p,s] = sum_b exp(E[b,p,s]),  E = W1 @ (X[b] @ W)
// ---------------------------------------------------------------------------
__global__ __launch_bounds__(256, 2)
void tabl_phase1(const float* __restrict__ X, const float* __restrict__ W1,
                 const float* __restrict__ W, float* __restrict__ S) {
  __shared__ float Xs[Tt * XS_S];    // X[b] transposed: [t][d]
  __shared__ float XWs[Dd * XW_S];   // XW = X[b] @ W : [d][s]
  __shared__ float W1t[Dd * W1_S];   // W1 transposed: [d][p]

  const int tid = threadIdx.x;

  // Load W1 transposed (once per block)
  for (int i = tid; i < Pp * Dd; i += 256) {
    int p = i / Dd, d = i % Dd;
    W1t[d * W1_S + p] = W1[i];
  }

  float sAcc[3][16];
#pragma unroll
  for (int j = 0; j < 3; ++j)
#pragma unroll
    for (int k = 0; k < 16; ++k) sAcc[j][k] = 0.f;

  const int b0 = blockIdx.x * NB1;
  for (int nb = 0; nb < NB1; ++nb) {
    const float* Xb = X + (size_t)(b0 + nb) * DT;

    // Load X[b] transposed into LDS (coalesced global reads)
    for (int i = tid; i < DT; i += 256) {
      int d = i / Tt, t = i % Tt;
      Xs[t * XS_S + d] = Xb[i];
    }
    __syncthreads();  // B1: Xs (and, first iter, W1t) ready; prior E readers of XWs done

    // XW[d][s] = sum_t Xs[t][d] * W[t][s]  -- 250 threads, 4x4 tiles
    if (tid < 250) {
      const int d0 = (tid / 25) * 4;
      const int s0 = (tid % 25) * 4;
      float acc[16];
#pragma unroll
      for (int k = 0; k < 16; ++k) acc[k] = 0.f;
#pragma unroll 4
      for (int t = 0; t < Tt; ++t) {
        const float4 xv = *reinterpret_cast<const float4*>(&Xs[t * XS_S + d0]);
        const float4 wv = *reinterpret_cast<const float4*>(&W[t * Tt + s0]);
        const float* xp = &xv.x;
        const float* wp = &wv.x;
#pragma unroll
        for (int i2 = 0; i2 < 4; ++i2)
#pragma unroll
          for (int j2 = 0; j2 < 4; ++j2)
            acc[i2 * 4 + j2] = fmaf(xp[i2], wp[j2], acc[i2 * 4 + j2]);
      }
#pragma unroll
      for (int i2 = 0; i2 < 4; ++i2)
#pragma unroll
        for (int j2 = 0; j2 < 4; ++j2)
          XWs[(d0 + i2) * XW_S + s0 + j2] = acc[i2 * 4 + j2];
    }
    __syncthreads();  // B2: XWs ready

    // E[p][s] = sum_d W1t[d][p] * XWs[d][s]; accumulate exp(E) in registers
#pragma unroll
    for (int j = 0; j < 3; ++j) {
      const int tile = tid + j * 256;
      if (tile < 750) {
        const int p0 = (tile / 25) * 4;
        const int s0 = (tile % 25) * 4;
        float e[16];
#pragma unroll
        for (int k = 0; k < 16; ++k) e[k] = 0.f;
#pragma unroll 2
        for (int d = 0; d < Dd; ++d) {
          const float4 av = *reinterpret_cast<const float4*>(&W1t[d * W1_S + p0]);
          const float4 bv = *reinterpret_cast<const float4*>(&XWs[d * XW_S + s0]);
          const float* ap = &av.x;
          const float* bp = &bv.x;
#pragma unroll
          for (int i2 = 0; i2 < 4; ++i2)
#pragma unroll
            for (int j2 = 0; j2 < 4; ++j2)
              e[i2 * 4 + j2] = fmaf(ap[i2], bp[j2], e[i2 * 4 + j2]);
        }
#pragma unroll
        for (int k = 0; k < 16; ++k) sAcc[j][k] += __expf(e[k]);
      }
    }
  }

  // One atomicAdd per (p,s) per block
#pragma unroll
  for (int j = 0; j < 3; ++j) {
    const int tile = tid + j * 256;
    if (tile < 750) {
      const int p0 = (tile / 25) * 4;
      const int s0 = (tile % 25) * 4;
#pragma unroll
      for (int i2 = 0; i2 < 4; ++i2)
#pragma unroll
        for (int j2 = 0; j2 < 4; ++j2)
          atomicAdd(&S[(p0 + i2) * Tt + s0 + j2], sAcc[j][i2 * 4 + j2]);
    }
  }
}

// ---------------------------------------------------------------------------
// Phase 2: recompute X1, E; A = exp(E)/S; tem = X1*((1-a) + a*A); Y = tem@W2 + bias
// One block per batch item.
// ---------------------------------------------------------------------------
__global__ __launch_bounds__(256, 2)
void tabl_phase2(const float* __restrict__ X, const float* __restrict__ W1,
                 const float* __restrict__ W, const float* __restrict__ alphap,
                 const float* __restrict__ W2, const float* __restrict__ bias,
                 const float* __restrict__ S, float* __restrict__ Y) {
  __shared__ float Xs[Tt * XS_S];
  __shared__ float XWs[Dd * XW_S];
  __shared__ float W1t[Dd * W1_S];
  __shared__ float temt[TCH * TM_S];  // tem chunk, transposed: [tl][p]

  const int tid = threadIdx.x;
  const float alpha = alphap[0];
  const float oma = 1.f - alpha;
  const int b = blockIdx.x;
  const float* Xb = X + (size_t)b * DT;

  for (int i = tid; i < Pp * Dd; i += 256) {
    int p = i / Dd, d = i % Dd;
    W1t[d * W1_S + p] = W1[i];
  }
  for (int i = tid; i < DT; i += 256) {
    int d = i / Tt, t = i % Tt;
    Xs[t * XS_S + d] = Xb[i];
  }
  __syncthreads();

  // XW = X[b] @ W
  if (tid < 250) {
    const int d0 = (tid / 25) * 4;
    const int s0 = (tid % 25) * 4;
    float acc[16];
#pragma unroll
    for (int k = 0; k < 16; ++k) acc[k] = 0.f;
#pragma unroll 4
    for (int t = 0; t < Tt; ++t) {
      const float4 xv = *reinterpret_cast<const float4*>(&Xs[t * XS_S + d0]);
      const float4 wv = *reinterpret_cast<const float4*>(&W[t * Tt + s0]);
      const float* xp = &xv.x;
      const float* wp = &wv.x;
#pragma unroll
      for (int i2 = 0; i2 < 4; ++i2)
#pragma unroll
        for (int j2 = 0; j2 < 4; ++j2)
          acc[i2 * 4 + j2] = fmaf(xp[i2], wp[j2], acc[i2 * 4 + j2]);
    }
#pragma unroll
    for (int i2 = 0; i2 < 4; ++i2)
#pragma unroll
      for (int j2 = 0; j2 < 4; ++j2)
        XWs[(d0 + i2) * XW_S + s0 + j2] = acc[i2 * 4 + j2];
  }
  __syncthreads();

  float yAcc[3][16];
#pragma unroll
  for (int j = 0; j < 3; ++j)
#pragma unroll
    for (int k = 0; k < 16; ++k) yAcc[j][k] = 0.f;

  for (int c = 0; c < 5; ++c) {
    const int tb = c * TCH;

    // tem chunk: X1 and E for t in [tb, tb+20), 150 threads x (4p x 4t) tiles
    if (tid < 150) {
      const int p0 = (tid / 5) * 4;
      const int tl0 = (tid % 5) * 4;
      float x1[16], e[16];
#pragma unroll
      for (int k = 0; k < 16; ++k) { x1[k] = 0.f; e[k] = 0.f; }
#pragma unroll 2
      for (int d = 0; d < Dd; ++d) {
        const float4 av = *reinterpret_cast<const float4*>(&W1t[d * W1_S + p0]);
        const float4 xwv = *reinterpret_cast<const float4*>(&XWs[d * XW_S + tb + tl0]);
        const float* ap = &av.x;
        const float* xwp = &xwv.x;
        float xsv[4];
#pragma unroll
        for (int j2 = 0; j2 < 4; ++j2) xsv[j2] = Xs[(tb + tl0 + j2) * XS_S + d];
#pragma unroll
        for (int i2 = 0; i2 < 4; ++i2)
#pragma unroll
          for (int j2 = 0; j2 < 4; ++j2) {
            x1[i2 * 4 + j2] = fmaf(ap[i2], xsv[j2], x1[i2 * 4 + j2]);
            e[i2 * 4 + j2] = fmaf(ap[i2], xwp[j2], e[i2 * 4 + j2]);
          }
      }
#pragma unroll
      for (int i2 = 0; i2 < 4; ++i2)
#pragma unroll
        for (int j2 = 0; j2 < 4; ++j2) {
          const int t = tb + tl0 + j2;
          const float sv = S[(p0 + i2) * Tt + t];
          const float a = __expf(e[i2 * 4 + j2]) / sv;
          const float g = oma + alpha * a;
          temt[(tl0 + j2) * TM_S + (p0 + i2)] = x1[i2 * 4 + j2] * g;
        }
    }
    __syncthreads();

    // Y += tem_chunk @ W2[tb:tb+20, :]
#pragma unroll
    for (int j = 0; j < 3; ++j) {
      const int tile = tid + j * 256;
      if (tile < 750) {
        const int p0 = (tile / 25) * 4;
        const int q0 = (tile % 25) * 4;
#pragma unroll 4
        for (int tl = 0; tl < TCH; ++tl) {
          const float4 tv = *reinterpret_cast<const float4*>(&temt[tl * TM_S + p0]);
          const float4 wv = *reinterpret_cast<const float4*>(&W2[(tb + tl) * Qq + q0]);
          const float* tp = &tv.x;
          const float* wp = &wv.x;
#pragma unroll
          for (int i2 = 0; i2 < 4; ++i2)
#pragma unroll
            for (int j2 = 0; j2 < 4; ++j2)
              yAcc[j][i2 * 4 + j2] = fmaf(tp[i2], wp[j2], yAcc[j][i2 * 4 + j2]);
        }
      }
    }
    __syncthreads();
  }

  // Epilogue: Y = yAcc + bias, vectorized stores
#pragma unroll
  for (int j = 0; j < 3; ++j) {
    const int tile = tid + j * 256;
    if (tile < 750) {
      const int p0 = (tile / 25) * 4;
      const int q0 = (tile % 25) * 4;
#pragma unroll
      for (int i2 = 0; i2 < 4; ++i2) {
        const float4 bv = *reinterpret_cast<const float4*>(&bias[(p0 + i2) * Qq + q0]);
        float4 ov;
        ov.x = yAcc[j][i2 * 4 + 0] + bv.x;
        ov.y = yAcc[j][i2 * 4 + 1] + bv.y;
        ov.z = yAcc[j][i2 * 4 + 2] + bv.z;
        ov.w = yAcc[j][i2 * 4 + 3] + bv.w;
        *reinterpret_cast<float4*>(&Y[(size_t)b * PQ + (p0 + i2) * Qq + q0]) = ov;
      }
    }
  }
}

extern "C" void kernel_launch(void* const* d_in, const int* in_sizes, int n_in,
                              void* d_out, int out_size, void* d_ws, size_t ws_size,
                              hipStream_t stream) {
  const float* X    = (const float*)d_in[0];
  const float* W1   = (const float*)d_in[1];
  const float* W    = (const float*)d_in[2];
  const float* al   = (const float*)d_in[3];
  const float* W2   = (const float*)d_in[4];
  const float* bias = (const float*)d_in[5];
  float* Y = (float*)d_out;
  float* S = (float*)d_ws;  // 12000 floats of exp-sum accumulators

  hipMemsetAsync(S, 0, PT * sizeof(float), stream);
  tabl_phase1<<<Bb / NB1, 256, 0, stream>>>(X, W1, W, S);
  tabl_phase2<<<Bb, 256, 0, stream>>>(X, W1, W, al, W2, bias, S, Y);
}

// Round 2
// 1086.526 us; speedup vs baseline: 1.5373x; 1.5373x over previous
//
#include <hip/hip_runtime.h>

// ---------------------------------------------------------------------------
// TABL: X1 = W1@X[b]; E = X1@W = W1@(X[b]@W); A = softmax over batch axis;
// tem = X1*(alpha*A + 1-alpha); Y = tem@W2 + bias.
// All GEMMs on bf16 MFMA 16x16x32, fp32 accumulate. Cross-batch softmax via
// S[p,s] = sum_b exp(E) accumulated in ws (phase1), consumed in phase2.
// ---------------------------------------------------------------------------

typedef __attribute__((ext_vector_type(8))) short short8;   // 8 bf16 = 4 VGPR
typedef __attribute__((ext_vector_type(4))) float floatx4;  // MFMA C/D

constexpr int Bb = 8192;

// LDS operand layouts (bf16 elems). A-store[m][k] / B-store[n][k], row-major.
// K(t)=100 padded to 128, stride 136 (2-way-conflict-free: 68 words, %32=4).
// K(d)=40  padded to 64,  stride 72  (36 words, %32=4).
constexpr int ST1 = 136;
constexpr int ST2 = 72;
constexpr int XB_B   = 48  * ST1 * 2;  // 13056  A: X[d][t]
constexpr int WT_B   = 112 * ST1 * 2;  // 30464  B: W^T[s][t]
constexpr int XWT_B  = 112 * ST2 * 2;  // 16128  B: XW^T[s][d]
constexpr int XT_B   = 112 * ST2 * 2;  // 16128  B: X^T[t][d]
constexpr int W1S_B  = 128 * ST2 * 2;  // 18432  A: W1[p][d]
constexpr int TEMA_B = 128 * ST1 * 2;  // 34816  A: tem[p][t]
constexpr int W2T_B  = 112 * ST1 * 2;  // 30464  B: W2^T[q][t]

// ws layout (bytes): S fp32[12000] @0; then prepped bf16 weights.
constexpr int WS_S_BYTES = 48000;
constexpr int WTG_OFF  = 48000;              // 30464
constexpr int W1G_OFF  = WTG_OFF + WT_B;     // 78464, 18432
constexpr int W2TG_OFF = W1G_OFF + W1S_B;    // 96896, 30464

__device__ __forceinline__ unsigned short f2bf(float f) {
  union { float f; unsigned u; } v; v.f = f;
  return (unsigned short)((v.u + 0x7FFFu + ((v.u >> 16) & 1u)) >> 16);
}

__device__ __forceinline__ void copy16(void* dst, const void* src, int nbytes, int tid) {
  int4* d = (int4*)dst; const int4* s = (const int4*)src;
  const int n = nbytes >> 4;
  for (int i = tid; i < n; i += 256) d[i] = s[i];
}

// Fill Xb (A-store X[d][t], stride ST1) from global X[b] (fp32 [40][100]).
// Pad zeroes are disjoint from data writes -> one pass, no extra sync.
__device__ __forceinline__ void fill_Xb(short* Xb, const float* Xg, int tid) {
  for (int i = tid; i < 8 * ST1; i += 256) {           // rows d in [40,48)
    int dd = 40 + i / ST1, tt = i % ST1; Xb[dd * ST1 + tt] = 0;
  }
  for (int i = tid; i < 40 * 36; i += 256) {           // cols t in [100,136)
    int dd = i / 36, tt = 100 + i % 36; Xb[dd * ST1 + tt] = 0;
  }
  const float4* x4 = (const float4*)Xg;
  for (int i = tid; i < 1000; i += 256) {
    float4 v = x4[i];
    float vv[4] = {v.x, v.y, v.z, v.w};
    int e0 = i * 4;
#pragma unroll
    for (int k = 0; k < 4; ++k) {
      int ee = e0 + k, d2 = ee / 100, t2 = ee - d2 * 100;
      Xb[d2 * ST1 + t2] = (short)f2bf(vv[k]);
    }
  }
}

// Fill Xt (B-store X^T[t][d], stride ST2) from global X[b].
__device__ __forceinline__ void fill_Xt(short* Xt, const float* Xg, int tid) {
  for (int i = tid; i < 12 * ST2; i += 256) {          // rows t in [100,112)
    int tt = 100 + i / ST2, dd = i % ST2; Xt[tt * ST2 + dd] = 0;
  }
  for (int i = tid; i < 100 * 32; i += 256) {          // cols d in [40,72)
    int tt = i / 32, dd = 40 + i % 32; Xt[tt * ST2 + dd] = 0;
  }
  const float4* x4 = (const float4*)Xg;
  for (int i = tid; i < 1000; i += 256) {
    float4 v = x4[i];
    float vv[4] = {v.x, v.y, v.z, v.w};
    int e0 = i * 4;
#pragma unroll
    for (int k = 0; k < 4; ++k) {
      int ee = e0 + k, d2 = ee / 100, t2 = ee - d2 * 100;
      Xt[t2 * ST2 + d2] = (short)f2bf(vv[k]);
    }
  }
}

// ---------------------------------------------------------------------------
// Prep: convert W, W1, W2 to zero-padded bf16 operand layouts in ws.
// ---------------------------------------------------------------------------
__global__ void tabl_prep(const float* __restrict__ W1, const float* __restrict__ W,
                          const float* __restrict__ W2, char* ws) {
  int i = blockIdx.x * 256 + threadIdx.x;
  if (i < 112 * ST1) {                         // W^T[s][t]
    int s = i / ST1, t = i % ST1;
    ((unsigned short*)(ws + WTG_OFF))[i] = (s < 100 && t < 100) ? f2bf(W[t * 100 + s]) : 0;
  } else if (i < 112 * ST1 + 128 * ST2) {      // W1[p][d]
    int j = i - 112 * ST1;
    int p = j / ST2, d = j % ST2;
    ((unsigned short*)(ws + W1G_OFF))[j] = (p < 120 && d < 40) ? f2bf(W1[p * 40 + d]) : 0;
  } else if (i < 112 * ST1 + 128 * ST2 + 112 * ST1) {  // W2^T[q][t]
    int j = i - 112 * ST1 - 128 * ST2;
    int q = j / ST1, t = j % ST1;
    ((unsigned short*)(ws + W2TG_OFF))[j] = (q < 100 && t < 100) ? f2bf(W2[t * 100 + q]) : 0;
  }
}

// ---------------------------------------------------------------------------
// Phase 1: S[p,s] += exp(E[b,p,s]) for 8 batches/block.
// LDS: W1s@0 (persist), Xb@18432, Wt@31488 (both restaged/batch),
//      XWt@18432 (aliases Xb+Wt head after their reads complete).
// ---------------------------------------------------------------------------
__global__ __launch_bounds__(256, 2)
void tabl_ph1(const float* __restrict__ X, const char* ws, float* S) {
  __shared__ __align__(16) char smem[61952];
  short* W1s = (short*)(smem);
  short* Xb  = (short*)(smem + 18432);
  short* Wt  = (short*)(smem + 31488);
  short* XWt = (short*)(smem + 18432);

  const int tid = threadIdx.x;
  const int wid = tid >> 6, lane = tid & 63;
  const int quad = lane >> 4, r = lane & 15;
  const floatx4 zed = {0.f, 0.f, 0.f, 0.f};

  floatx4 sacc[14];
#pragma unroll
  for (int j = 0; j < 14; ++j) sacc[j] = zed;

  copy16(W1s, ws + W1G_OFF, W1S_B, tid);

  const int b0 = blockIdx.x * 8;
  for (int nb = 0; nb < 8; ++nb) {
    const float* Xg = X + (size_t)(b0 + nb) * 4000;
    copy16(Wt, ws + WTG_OFF, WT_B, tid);
    fill_Xb(Xb, Xg, tid);
    __syncthreads();

    // XW = X@W : M=d(3 tiles), N=s(7 tiles), K=t(4 steps)
    floatx4 xw[6];
#pragma unroll
    for (int j = 0; j < 6; ++j) xw[j] = zed;
#pragma unroll
    for (int j = 0; j < 6; ++j) {
      int tt = wid + j * 4;
      if (tt < 21) {
        int mi = tt / 7, ni = tt % 7;
#pragma unroll
        for (int ks = 0; ks < 4; ++ks) {
          short8 a = *(const short8*)&Xb[(mi * 16 + r) * ST1 + ks * 32 + quad * 8];
          short8 bf = *(const short8*)&Wt[(ni * 16 + r) * ST1 + ks * 32 + quad * 8];
          xw[j] = __builtin_amdgcn_mfma_f32_16x16x32_bf16(a, bf, xw[j], 0, 0, 0);
        }
      }
    }
    __syncthreads();  // Xb/Wt reads done; safe to overwrite with XWt

    for (int i = tid; i < 112 * 24; i += 256) {  // XWt pad cols [48,72)
      int rr = i / 24, cc = 48 + i % 24; XWt[rr * ST2 + cc] = 0;
    }
#pragma unroll
    for (int j = 0; j < 6; ++j) {
      int tt = wid + j * 4;
      if (tt < 21) {
        int mi = tt / 7, ni = tt % 7;
        short4 pk;
        pk.x = (short)f2bf(xw[j][0]); pk.y = (short)f2bf(xw[j][1]);
        pk.z = (short)f2bf(xw[j][2]); pk.w = (short)f2bf(xw[j][3]);
        // D[d][s] -> XWt[s][d], 4 consecutive d packed into one 8B store
        *(short4*)&XWt[(ni * 16 + r) * ST2 + mi * 16 + quad * 4] = pk;
      }
    }
    __syncthreads();

    // E = W1@XW : M=p(8 tiles), N=s(7 tiles), K=d(2 steps); accumulate exp
#pragma unroll
    for (int jj = 0; jj < 14; ++jj) {
      int pos = wid + jj * 4;
      int mi = pos / 7, ni = pos % 7;
      floatx4 e = zed;
#pragma unroll
      for (int ks = 0; ks < 2; ++ks) {
        short8 a = *(const short8*)&W1s[(mi * 16 + r) * ST2 + ks * 32 + quad * 8];
        short8 bf = *(const short8*)&XWt[(ni * 16 + r) * ST2 + ks * 32 + quad * 8];
        e = __builtin_amdgcn_mfma_f32_16x16x32_bf16(a, bf, e, 0, 0, 0);
      }
#pragma unroll
      for (int c = 0; c < 4; ++c) sacc[jj][c] += __expf(e[c]);
    }
    __syncthreads();  // XWt reads done before next batch restages over it
  }

#pragma unroll
  for (int jj = 0; jj < 14; ++jj) {
    int pos = wid + jj * 4;
    int mi = pos / 7, ni = pos % 7;
    int s = ni * 16 + r;
#pragma unroll
    for (int c = 0; c < 4; ++c) {
      int p = mi * 16 + quad * 4 + c;
      if (p < 120 && s < 100) atomicAdd(&S[p * 100 + s], sacc[jj][c]);
    }
  }
}

// ---------------------------------------------------------------------------
// Phase 2: one batch per block. Phased/aliased LDS inside 65280 B:
//  P1: Xb@0, Wt@13056 -> XW regs; XWt@43520
//  P2: Xt@0, W1s@16128 (+XWt) -> X1,E regs -> tem regs
//  P3/4: temA@0, W2t@34816 -> Y
// ---------------------------------------------------------------------------
__global__ __launch_bounds__(256, 2)
void tabl_ph2(const float* __restrict__ X, const char* ws,
              const float* __restrict__ alphap, const float* __restrict__ bias,
              float* __restrict__ Y) {
  __shared__ __align__(16) char smem[65280];
  short* Xb   = (short*)(smem);
  short* Wt   = (short*)(smem + 13056);
  short* XWt  = (short*)(smem + 43520);
  short* Xt   = (short*)(smem);
  short* W1s  = (short*)(smem + 16128);
  short* temA = (short*)(smem);
  short* W2t  = (short*)(smem + 34816);
  const float* S = (const float*)ws;

  const int tid = threadIdx.x;
  const int wid = tid >> 6, lane = tid & 63;
  const int quad = lane >> 4, r = lane & 15;
  const floatx4 zed = {0.f, 0.f, 0.f, 0.f};

  const int b = blockIdx.x;
  const float* Xg = X + (size_t)b * 4000;
  const float alpha = alphap[0];
  const float oma = 1.f - alpha;

  copy16(Wt, ws + WTG_OFF, WT_B, tid);
  fill_Xb(Xb, Xg, tid);
  __syncthreads();

  // XW = X@W
  floatx4 xw[6];
#pragma unroll
  for (int j = 0; j < 6; ++j) xw[j] = zed;
#pragma unroll
  for (int j = 0; j < 6; ++j) {
    int tt = wid + j * 4;
    if (tt < 21) {
      int mi = tt / 7, ni = tt % 7;
#pragma unroll
      for (int ks = 0; ks < 4; ++ks) {
        short8 a = *(const short8*)&Xb[(mi * 16 + r) * ST1 + ks * 32 + quad * 8];
        short8 bf = *(const short8*)&Wt[(ni * 16 + r) * ST1 + ks * 32 + quad * 8];
        xw[j] = __builtin_amdgcn_mfma_f32_16x16x32_bf16(a, bf, xw[j], 0, 0, 0);
      }
    }
  }
  __syncthreads();  // Xb/Wt dead

  // Stage XWt (from regs), Xt (re-read X, L2-hot), W1s
  for (int i = tid; i < 112 * 24; i += 256) {
    int rr = i / 24, cc = 48 + i % 24; XWt[rr * ST2 + cc] = 0;
  }
#pragma unroll
  for (int j = 0; j < 6; ++j) {
    int tt = wid + j * 4;
    if (tt < 21) {
      int mi = tt / 7, ni = tt % 7;
      short4 pk;
      pk.x = (short)f2bf(xw[j][0]); pk.y = (short)f2bf(xw[j][1]);
      pk.z = (short)f2bf(xw[j][2]); pk.w = (short)f2bf(xw[j][3]);
      *(short4*)&XWt[(ni * 16 + r) * ST2 + mi * 16 + quad * 4] = pk;
    }
  }
  copy16(W1s, ws + W1G_OFF, W1S_B, tid);
  fill_Xt(Xt, Xg, tid);
  __syncthreads();

  // X1 = W1@X, E = W1@XW (shared A frags), then tem in regs
  floatx4 tem[14];
#pragma unroll
  for (int jj = 0; jj < 14; ++jj) {
    int pos = wid + jj * 4;
    int mi = pos / 7, ni = pos % 7;
    floatx4 x1 = zed, e = zed;
#pragma unroll
    for (int ks = 0; ks < 2; ++ks) {
      short8 a  = *(const short8*)&W1s[(mi * 16 + r) * ST2 + ks * 32 + quad * 8];
      short8 bx = *(const short8*)&Xt[(ni * 16 + r) * ST2 + ks * 32 + quad * 8];
      short8 bw = *(const short8*)&XWt[(ni * 16 + r) * ST2 + ks * 32 + quad * 8];
      x1 = __builtin_amdgcn_mfma_f32_16x16x32_bf16(a, bx, x1, 0, 0, 0);
      e  = __builtin_amdgcn_mfma_f32_16x16x32_bf16(a, bw, e, 0, 0, 0);
    }
    int scol = ni * 16 + r;
#pragma unroll
    for (int c = 0; c < 4; ++c) {
      int p = mi * 16 + quad * 4 + c;
      float v = 0.f;
      if (p < 120 && scol < 100) {
        float sv = S[p * 100 + scol];
        float aval = __expf(e[c]) / sv;
        v = x1[c] * (oma + alpha * aval);
      }
      tem[jj][c] = v;  // 0 in pad region keeps temA NaN-free
    }
  }
  __syncthreads();  // Xt/W1s/XWt dead

  // temA[p][t] + W2t staging
  for (int i = tid; i < 128 * 16; i += 256) {  // temA pad cols [112,128)
    int rr = i / 16, cc = 112 + i % 16; temA[rr * ST1 + cc] = 0;
  }
#pragma unroll
  for (int jj = 0; jj < 14; ++jj) {
    int pos = wid + jj * 4;
    int mi = pos / 7, ni = pos % 7;
    int tcol = ni * 16 + r;
#pragma unroll
    for (int c = 0; c < 4; ++c) {
      int p = mi * 16 + quad * 4 + c;
      temA[p * ST1 + tcol] = (short)f2bf(tem[jj][c]);
    }
  }
  copy16(W2t, ws + W2TG_OFF, W2T_B, tid);
  __syncthreads();

  // Y = tem@W2 + bias : M=p(8), N=q(7), K=t(4 steps)
#pragma unroll
  for (int jj = 0; jj < 14; ++jj) {
    int pos = wid + jj * 4;
    int mi = pos / 7, ni = pos % 7;
    floatx4 y = zed;
#pragma unroll
    for (int ks = 0; ks < 4; ++ks) {
      short8 a  = *(const short8*)&temA[(mi * 16 + r) * ST1 + ks * 32 + quad * 8];
      short8 bf = *(const short8*)&W2t[(ni * 16 + r) * ST1 + ks * 32 + quad * 8];
      y = __builtin_amdgcn_mfma_f32_16x16x32_bf16(a, bf, y, 0, 0, 0);
    }
    int qc = ni * 16 + r;
    if (qc < 100) {
#pragma unroll
      for (int c = 0; c < 4; ++c) {
        int p = mi * 16 + quad * 4 + c;
        if (p < 120) {
          int idx = p * 100 + qc;
          Y[(size_t)b * 12000 + idx] = y[c] + bias[idx];
        }
      }
    }
  }
}

extern "C" void kernel_launch(void* const* d_in, const int* in_sizes, int n_in,
                              void* d_out, int out_size, void* d_ws, size_t ws_size,
                              hipStream_t stream) {
  const float* X    = (const float*)d_in[0];
  const float* W1   = (const float*)d_in[1];
  const float* W    = (const float*)d_in[2];
  const float* al   = (const float*)d_in[3];
  const float* W2   = (const float*)d_in[4];
  const float* bias = (const float*)d_in[5];
  float* Y = (float*)d_out;
  char* ws = (char*)d_ws;

  hipMemsetAsync(ws, 0, WS_S_BYTES, stream);                 // S = 0
  int prep_elems = 112 * ST1 + 128 * ST2 + 112 * ST1;
  tabl_prep<<<(prep_elems + 255) / 256, 256, 0, stream>>>(W1, W, W2, ws);
  tabl_ph1<<<Bb / 8, 256, 0, stream>>>(X, ws, (float*)ws);
  tabl_ph2<<<Bb, 256, 0, stream>>>(X, ws, al, bias, Y);
}